// Round 6
// baseline (1183.478 us; speedup 1.0000x reference)
//
#include <hip/hip_runtime.h>
#include <hip/hip_bf16.h>

#define N_   100000
#define E_   3200000
#define IN_  128
#define H_   256
#define OUT_ 256
#define G_   64
#define EPSV 1e-5f

#define MT1   1563            // ceil(N/64) M-tiles
#define GB1   (MT1*4)         // gemm1 blocks (4 column tiles)
#define FILLB 12891           // ceil((E+N)/256)

__device__ __forceinline__ unsigned short f2bf(float x){
  unsigned u = __float_as_uint(x);
  return (unsigned short)((u + 0x7FFFu + ((u >> 16) & 1u)) >> 16);
}
__device__ __forceinline__ float bf2f(unsigned short u){
  return __uint_as_float(((unsigned)u) << 16);
}
__device__ __forceinline__ float bflo(unsigned v){ return __uint_as_float(v << 16); }
__device__ __forceinline__ float bfhi(unsigned v){ return __uint_as_float(v & 0xffff0000u); }

// ---------------- CSR build ----------------
__global__ void k_count(const int* __restrict__ dst, int* __restrict__ deg){
  int e = blockIdx.x*256 + threadIdx.x;
  if (e < E_) atomicAdd(&deg[dst[e]], 1);
}

__global__ __launch_bounds__(1024) void k_scan1(const int* __restrict__ deg, int* __restrict__ rowp,
                                                int* __restrict__ bsums){
  __shared__ int s[1024];
  int t = threadIdx.x;
  int i = blockIdx.x*1024 + t;
  int v = (i < N_) ? (deg[i] + 1) : 0;   // +1 = self loop
  s[t] = v;
  __syncthreads();
  for (int o = 1; o < 1024; o <<= 1){
    int x = (t >= o) ? s[t-o] : 0;
    __syncthreads();
    s[t] += x;
    __syncthreads();
  }
  if (i < N_) rowp[i+1] = s[t];
  if (t == 1023) bsums[blockIdx.x] = s[1023];
}

__global__ void k_scan2(int* __restrict__ bsums, int nb){
  __shared__ int s[128];
  int t = threadIdx.x;
  int v = (t < nb) ? bsums[t] : 0;
  s[t] = v;
  __syncthreads();
  for (int o = 1; o < 128; o <<= 1){
    int x = (t >= o) ? s[t-o] : 0;
    __syncthreads();
    s[t] += x;
    __syncthreads();
  }
  if (t < nb) bsums[t] = s[t] - v;       // exclusive
}

__global__ __launch_bounds__(1024) void k_scan3(const int* __restrict__ deg, int* __restrict__ rowp,
                                                const int* __restrict__ bsums, int* __restrict__ cursor){
  int t = threadIdx.x;
  int i = blockIdx.x*1024 + t;
  if (i < N_){
    int rp = rowp[i+1] + bsums[blockIdx.x];
    rowp[i+1] = rp;
    cursor[i] = rp - (deg[i] + 1);
  }
  if (i == 0) rowp[0] = 0;
}

// ---------------- shared GEMM tile body ----------------
template<int K, bool BNIN>
__device__ __forceinline__ void gemm_tile(float (*As)[68], float (*Ws)[68],
                                          const float* __restrict__ A, const float* __restrict__ W,
                                          unsigned short* __restrict__ hb, int nrows,
                                          const float* __restrict__ a_s, const float* __restrict__ a_d,
                                          float* __restrict__ ssrc, float* __restrict__ sdst,
                                          const float* __restrict__ bnsc, const float* __restrict__ bnsh,
                                          int bx, int by, int t){
  const int bm = bx * 64;
  const int bn = by * 64;
  const int lm = t >> 2,  lk = (t & 3) * 4;    // A staging
  const int wk = t >> 4,  wn = (t & 15) * 4;   // W staging
  const int tm = (t >> 4) * 4, tn = (t & 15) * 4; // compute tile
  float acc[4][4];
  #pragma unroll
  for (int i=0;i<4;i++){
    #pragma unroll
    for (int j=0;j<4;j++) acc[i][j]=0.f;
  }
  for (int kb = 0; kb < K; kb += 16){
    const int arow = bm + lm;
    float4 av = make_float4(0.f,0.f,0.f,0.f);
    if (arow < nrows){
      av = *reinterpret_cast<const float4*>(A + (size_t)arow*K + kb + lk);
      if (BNIN){
        const float4 sc = *reinterpret_cast<const float4*>(bnsc + kb + lk);
        const float4 sh = *reinterpret_cast<const float4*>(bnsh + kb + lk);
        av.x = fmaxf(av.x*sc.x + sh.x, 0.f);
        av.y = fmaxf(av.y*sc.y + sh.y, 0.f);
        av.z = fmaxf(av.z*sc.z + sh.z, 0.f);
        av.w = fmaxf(av.w*sc.w + sh.w, 0.f);
      }
    }
    const float4 wv = *reinterpret_cast<const float4*>(W + (size_t)(kb + wk)*256 + bn + wn);
    __syncthreads();
    As[lk+0][lm]=av.x; As[lk+1][lm]=av.y; As[lk+2][lm]=av.z; As[lk+3][lm]=av.w;
    *reinterpret_cast<float4*>(&Ws[wk][wn]) = wv;
    __syncthreads();
    #pragma unroll
    for (int k=0;k<16;k++){
      const float4 a  = *reinterpret_cast<const float4*>(&As[k][tm]);
      const float4 bv = *reinterpret_cast<const float4*>(&Ws[k][tn]);
      acc[0][0]+=a.x*bv.x; acc[0][1]+=a.x*bv.y; acc[0][2]+=a.x*bv.z; acc[0][3]+=a.x*bv.w;
      acc[1][0]+=a.y*bv.x; acc[1][1]+=a.y*bv.y; acc[1][2]+=a.y*bv.z; acc[1][3]+=a.y*bv.w;
      acc[2][0]+=a.z*bv.x; acc[2][1]+=a.z*bv.y; acc[2][2]+=a.z*bv.z; acc[2][3]+=a.z*bv.w;
      acc[3][0]+=a.w*bv.x; acc[3][1]+=a.w*bv.y; acc[3][2]+=a.w*bv.z; acc[3][3]+=a.w*bv.w;
    }
  }
  #pragma unroll
  for (int i=0;i<4;i++){
    const int row = bm + tm + i;
    if (row < nrows){
      ushort4 o;
      o.x = f2bf(acc[i][0]); o.y = f2bf(acc[i][1]);
      o.z = f2bf(acc[i][2]); o.w = f2bf(acc[i][3]);
      *reinterpret_cast<ushort4*>(hb + (size_t)row*256 + bn + tn) = o;
    }
  }
  // fused partial attention dots over this block's 64-col slice
  const float4 asv = *reinterpret_cast<const float4*>(a_s + bn + tn);
  const float4 adv = *reinterpret_cast<const float4*>(a_d + bn + tn);
  #pragma unroll
  for (int i=0;i<4;i++){
    float ps = acc[i][0]*asv.x + acc[i][1]*asv.y + acc[i][2]*asv.z + acc[i][3]*asv.w;
    float pd = acc[i][0]*adv.x + acc[i][1]*adv.y + acc[i][2]*adv.z + acc[i][3]*adv.w;
    #pragma unroll
    for (int o=1;o<16;o<<=1){ ps += __shfl_xor(ps, o, 64); pd += __shfl_xor(pd, o, 64); }
    if ((t & 15) == 0){
      const int row = bm + tm + i;
      if (row < nrows){ atomicAdd(&ssrc[row], ps); atomicAdd(&sdst[row], pd); }
    }
  }
}

// layer-2 GEMM (BN1+relu fused on A-load), 2D grid
template<int K, bool BNIN>
__global__ __launch_bounds__(256) void k_gemm(const float* __restrict__ A, const float* __restrict__ W,
                                              unsigned short* __restrict__ hb, int nrows,
                                              const float* __restrict__ a_s, const float* __restrict__ a_d,
                                              float* __restrict__ ssrc, float* __restrict__ sdst,
                                              const float* __restrict__ bnsc, const float* __restrict__ bnsh){
  __shared__ float As[16][68];
  __shared__ float Ws[16][68];
  gemm_tile<K,BNIN>(As, Ws, A, W, hb, nrows, a_s, a_d, ssrc, sdst, bnsc, bnsh,
                    blockIdx.x, blockIdx.y, threadIdx.x);
}

// fused GEMM1 + CSR fill (mod-3 interleave, 1 gemm : 2 fill)
__global__ __launch_bounds__(256) void k_gemm1_fill(const float* __restrict__ A, const float* __restrict__ W,
                                                    unsigned short* __restrict__ hb,
                                                    const float* __restrict__ a_s, const float* __restrict__ a_d,
                                                    float* __restrict__ ssrc, float* __restrict__ sdst,
                                                    const int* __restrict__ ei, int* __restrict__ cursor,
                                                    int* __restrict__ col){
  __shared__ float As[16][68];
  __shared__ float Ws[16][68];
  const int bid = blockIdx.x;
  int fill_idx;
  if (bid % 3 == 0){
    const int g = bid / 3;
    if (g < GB1){
      gemm_tile<IN_,false>(As, Ws, A, W, hb, N_, a_s, a_d, ssrc, sdst, nullptr, nullptr,
                           g % MT1, g / MT1, threadIdx.x);
      return;
    }
    fill_idx = bid - GB1;
  } else {
    fill_idx = bid - min(bid/3 + 1, GB1);
  }
  const int e = fill_idx*256 + threadIdx.x;
  if (e < E_){
    const int d = ei[E_ + e];
    const int pos = atomicAdd(&cursor[d], 1);
    col[pos] = ei[e];
  } else if (e < E_ + N_){
    const int i = e - E_;
    const int pos = atomicAdd(&cursor[i], 1);
    col[pos] = i;
  }
}

// ---------------- GAT aggregation (grid-stride) + fused BN stats ----------------
// Phase A: 64 lanes compute 64 edge weights in parallel, stash (w,src) in LDS (zero-padded).
// Phase B: each HALF-wave (32 lanes x 16B) gathers one FULL 512B row per edge -> one
// dwordx4 instruction covers 2 edges (1KB); 2 pairs unrolled = 4 edges in flight.
// Cross-half shfl_xor(32) merges the halves' accumulators once per node.
__global__ __launch_bounds__(256) void k_agg(const unsigned short* __restrict__ hb, const int* __restrict__ col,
                                             const int* __restrict__ rowp, const float* __restrict__ ssrc,
                                             const float* __restrict__ sdst, const float* __restrict__ bias,
                                             float* __restrict__ out, float* __restrict__ bnsum,
                                             float* __restrict__ bnsq){
  __shared__ float sbn[512];
  __shared__ __align__(16) float2 wsb[4][64];   // (w, bits(src)) per wave
  const int t = threadIdx.x;
  sbn[t] = 0.f; sbn[t+256] = 0.f;
  const int lane = t & 63;
  const int wid  = t >> 6;
  const int half = lane >> 5;        // 0 or 1: which edge of the pair
  const int l32  = lane & 31;        // 16B chunk within the row
  const int fb   = l32*8 + half*4;   // this lane's output float4 feature base
  const float4 bbv = *reinterpret_cast<const float4*>(bias + fb);
  float s0=0.f,s1=0.f,s2=0.f,s3=0.f, q0=0.f,q1=0.f,q2=0.f,q3=0.f;
  __syncthreads();
  for (int node = blockIdx.x*4 + wid; node < N_; node += gridDim.x*4){
    const int start = rowp[node];
    const int end   = rowp[node+1];
    const float sd  = sdst[node];
    float den_l = 0.f;
    float a0=0.f,a1=0.f,a2=0.f,a3=0.f,a4=0.f,a5=0.f,a6=0.f,a7=0.f;
    for (int base = start; base < end; base += 64){
      // Phase A: lane-parallel edge weights (zero-padded beyond end)
      const int p = base + lane;
      float w = 0.f; int s = 0;
      if (p < end){
        s = col[p];
        float e = ssrc[s] + sd;
        e = e > 0.f ? e : 0.2f*e;
        w = expf(e);
      }
      den_l += w;
      wsb[wid][lane] = make_float2(w, __int_as_float(s));
      // Phase B: full-row gathers, 2 edges per dwordx4, 4 edges per iteration
      const int m = (end - base < 64) ? (end - base) : 64;
      for (int j = 0; j < m; j += 4){
        const float2 qa = wsb[wid][j + half];
        const float2 qb = wsb[wid][j + 2 + half];
        const float wa = qa.x; const int va = __float_as_int(qa.y);
        const float wb = qb.x; const int vb = __float_as_int(qb.y);
        const uint4 A = *reinterpret_cast<const uint4*>(hb + (size_t)va*256 + l32*8);
        const uint4 B = *reinterpret_cast<const uint4*>(hb + (size_t)vb*256 + l32*8);
        a0 += wa*bflo(A.x); a1 += wa*bfhi(A.x);
        a2 += wa*bflo(A.y); a3 += wa*bfhi(A.y);
        a4 += wa*bflo(A.z); a5 += wa*bfhi(A.z);
        a6 += wa*bflo(A.w); a7 += wa*bfhi(A.w);
        a0 += wb*bflo(B.x); a1 += wb*bfhi(B.x);
        a2 += wb*bflo(B.y); a3 += wb*bfhi(B.y);
        a4 += wb*bflo(B.z); a5 += wb*bfhi(B.z);
        a6 += wb*bflo(B.w); a7 += wb*bfhi(B.w);
      }
    }
    // wave-reduce denominator (once per node)
    float den = den_l;
    #pragma unroll
    for (int o = 32; o; o >>= 1) den += __shfl_xor(den, o, 64);
    const float inv = 1.f/den;
    // merge the two half-wave accumulators
    a0 += __shfl_xor(a0, 32, 64); a1 += __shfl_xor(a1, 32, 64);
    a2 += __shfl_xor(a2, 32, 64); a3 += __shfl_xor(a3, 32, 64);
    a4 += __shfl_xor(a4, 32, 64); a5 += __shfl_xor(a5, 32, 64);
    a6 += __shfl_xor(a6, 32, 64); a7 += __shfl_xor(a7, 32, 64);
    float4 r;
    r.x = (half ? a4 : a0)*inv + bbv.x;
    r.y = (half ? a5 : a1)*inv + bbv.y;
    r.z = (half ? a6 : a2)*inv + bbv.z;
    r.w = (half ? a7 : a3)*inv + bbv.w;
    *reinterpret_cast<float4*>(out + (size_t)node*256 + fb) = r;
    s0 += r.x; s1 += r.y; s2 += r.z; s3 += r.w;
    q0 += r.x*r.x; q1 += r.y*r.y; q2 += r.z*r.z; q3 += r.w*r.w;
  }
  // BN partial reduce: LDS across the block's 4 waves, then one flush
  atomicAdd(&sbn[fb+0], s0); atomicAdd(&sbn[fb+1], s1);
  atomicAdd(&sbn[fb+2], s2); atomicAdd(&sbn[fb+3], s3);
  atomicAdd(&sbn[256+fb+0], q0); atomicAdd(&sbn[256+fb+1], q1);
  atomicAdd(&sbn[256+fb+2], q2); atomicAdd(&sbn[256+fb+3], q3);
  __syncthreads();
  atomicAdd(&bnsum[t], sbn[t]);
  atomicAdd(&bnsq[t],  sbn[256+t]);
}

__global__ void k_bnprep(const float* __restrict__ g, const float* __restrict__ be,
                         float* __restrict__ bsum, float* __restrict__ bsq){
  const int f = threadIdx.x;
  const float mean = bsum[f] * (1.0f/N_);
  const float var  = bsq[f]  * (1.0f/N_) - mean*mean;
  const float sc = g[f] / sqrtf(var + EPSV);
  bsum[f] = sc;
  bsq[f]  = be[f] - mean*sc;
}

// ---------------- global mean pool (fused BN2+relu) ----------------
__global__ __launch_bounds__(256) void k_pool(const float* __restrict__ x, const int* __restrict__ batch,
                                              const float* __restrict__ sc, const float* __restrict__ sh,
                                              float* __restrict__ psum, float* __restrict__ pcnt){
  const int f = threadIdx.x;
  const float scf = sc[f], shf = sh[f];
  const int RPB = (N_ + gridDim.x - 1) / gridDim.x;
  const int r0 = blockIdx.x * RPB;
  const int r1 = min(r0 + RPB, N_);
  if (r0 >= N_) return;
  float local = 0.f, c = 0.f;
  int curg = -1;
  for (int r = r0; r < r1; ++r){
    const int g = batch[r];
    if (g != curg){
      if (curg >= 0){
        atomicAdd(&psum[curg*256 + f], local);
        if (f == 0) atomicAdd(&pcnt[curg], c);
      }
      curg = g; local = 0.f; c = 0.f;
    }
    local += fmaxf(x[(size_t)r*256 + f]*scf + shf, 0.f);
    c += 1.f;
  }
  if (curg >= 0){
    atomicAdd(&psum[curg*256 + f], local);
    if (f == 0) atomicAdd(&pcnt[curg], c);
  }
}

// ---------------- FC head ----------------
__global__ __launch_bounds__(256) void k_fc1(const float* __restrict__ psum, const float* __restrict__ pcnt,
                                             const float* __restrict__ w, const float* __restrict__ b,
                                             float* __restrict__ z){
  __shared__ float p[256];
  const int g = blockIdx.x, f = threadIdx.x;
  const float cnt = fmaxf(pcnt[g], 1.f);
  p[f] = psum[g*256 + f] / cnt;
  __syncthreads();
  float acc = b[f];
  #pragma unroll 8
  for (int k = 0; k < 256; ++k) acc += p[k] * w[k*256 + f];
  z[g*256 + f] = fmaxf(acc, 0.f);
}

__global__ __launch_bounds__(128) void k_fc2(const float* __restrict__ zin, const float* __restrict__ w,
                                             const float* __restrict__ b, float* __restrict__ z){
  __shared__ float p[256];
  const int g = blockIdx.x, f = threadIdx.x;
  p[f] = zin[g*256 + f];
  p[f+128] = zin[g*256 + f + 128];
  __syncthreads();
  float acc = b[f];
  #pragma unroll 8
  for (int k = 0; k < 256; ++k) acc += p[k] * w[k*128 + f];
  z[g*128 + f] = fmaxf(acc, 0.f);
}

__global__ __launch_bounds__(64) void k_fc3(const float* __restrict__ zin, const float* __restrict__ w,
                                            const float* __restrict__ b, float* __restrict__ out){
  const int g = threadIdx.x;   // 64 graphs
  float acc = b[0];
  #pragma unroll 8
  for (int k = 0; k < 128; ++k) acc += zin[g*128 + k] * w[k];
  out[g] = acc;
}

// ---------------- launch ----------------
extern "C" void kernel_launch(void* const* d_in, const int* in_sizes, int n_in,
                              void* d_out, int out_size, void* d_ws, size_t ws_size,
                              hipStream_t stream){
  (void)in_sizes; (void)n_in; (void)out_size; (void)ws_size;
  const float* x    = (const float*)d_in[0];
  const float* W1   = (const float*)d_in[1];
  const float* a_s1 = (const float*)d_in[2];
  const float* a_d1 = (const float*)d_in[3];
  const float* b1   = (const float*)d_in[4];
  const float* g1   = (const float*)d_in[5];
  const float* be1  = (const float*)d_in[6];
  const float* W2   = (const float*)d_in[7];
  const float* a_s2 = (const float*)d_in[8];
  const float* a_d2 = (const float*)d_in[9];
  const float* b2   = (const float*)d_in[10];
  const float* g2   = (const float*)d_in[11];
  const float* be2  = (const float*)d_in[12];
  const float* fc1w = (const float*)d_in[13];
  const float* fc1b = (const float*)d_in[14];
  const float* fc2w = (const float*)d_in[15];
  const float* fc2b = (const float*)d_in[16];
  const float* fc3w = (const float*)d_in[17];
  const float* fc3b = (const float*)d_in[18];
  const int*   ei   = (const int*)d_in[19];
  const int*   batch= (const int*)d_in[20];
  float* out = (float*)d_out;

  char* ws = (char*)d_ws;
  size_t off = 0;
  auto alloc = [&](size_t bytes)->char*{
    char* p = ws + off;
    off += (bytes + 255) & ~(size_t)255;
    return p;
  };
  unsigned short* hb = (unsigned short*)alloc((size_t)N_*256*2);  // bf16 h (both layers)
  float* agg    = (float*)alloc((size_t)N_*256*4);
  int*   col    = (int*)  alloc((size_t)(E_+N_)*4);
  int*   rowp   = (int*)  alloc((size_t)(N_+1)*4);
  int*   deg    = (int*)  alloc((size_t)N_*4);
  int*   cursor = (int*)  alloc((size_t)N_*4);
  float* ssrc   = (float*)alloc((size_t)N_*4);
  float* sdst   = (float*)alloc((size_t)N_*4);
  float* bns1   = (float*)alloc(512*4);            // sum|sumsq -> scale|shift (layer1)
  float* bns2   = (float*)alloc(512*4);            // layer2
  float* pooled = (float*)alloc((G_*256 + G_)*4);  // sums | counts
  float* z1     = (float*)alloc(G_*256*4);
  float* z2     = (float*)alloc(G_*128*4);
  int*   bsums  = (int*)  alloc(1024*4);

  const int NCHUNK = (N_ + 1023) / 1024;   // 98

  // ---- CSR prefix (count + scans) ----
  hipMemsetAsync(deg, 0, (size_t)N_*4, stream);
  k_count<<<(E_+255)/256, 256, 0, stream>>>(ei + E_, deg);
  k_scan1<<<NCHUNK, 1024, 0, stream>>>(deg, rowp, bsums);
  k_scan2<<<1, 128, 0, stream>>>(bsums, NCHUNK);
  k_scan3<<<NCHUNK, 1024, 0, stream>>>(deg, rowp, bsums, cursor);

  // ---- layer 1: GEMM1 co-scheduled with CSR fill ----
  hipMemsetAsync(ssrc, 0, (size_t)N_*4, stream);
  hipMemsetAsync(sdst, 0, (size_t)N_*4, stream);
  hipMemsetAsync(bns1, 0, 512*4, stream);
  k_gemm1_fill<<<GB1 + FILLB, 256, 0, stream>>>(x, W1, hb, a_s1, a_d1, ssrc, sdst, ei, cursor, col);
  k_agg<<<2048, 256, 0, stream>>>(hb, col, rowp, ssrc, sdst, b1, agg, bns1, bns1 + 256);
  k_bnprep<<<1, 256, 0, stream>>>(g1, be1, bns1, bns1 + 256);

  // ---- layer 2 (BN1+relu fused into GEMM A-load) ----
  hipMemsetAsync(ssrc, 0, (size_t)N_*4, stream);
  hipMemsetAsync(sdst, 0, (size_t)N_*4, stream);
  hipMemsetAsync(bns2, 0, 512*4, stream);
  k_gemm<H_, true><<<dim3(MT1, 4), 256, 0, stream>>>(agg, W2, hb, N_, a_s2, a_d2, ssrc, sdst, bns1, bns1 + 256);
  k_agg<<<2048, 256, 0, stream>>>(hb, col, rowp, ssrc, sdst, b2, agg, bns2, bns2 + 256);
  k_bnprep<<<1, 256, 0, stream>>>(g2, be2, bns2, bns2 + 256);

  // ---- pool (BN2+relu fused) + head ----
  hipMemsetAsync(pooled, 0, (size_t)(G_*256 + G_)*4, stream);
  k_pool<<<512, 256, 0, stream>>>(agg, batch, bns2, bns2 + 256, pooled, pooled + G_*256);
  k_fc1<<<G_, 256, 0, stream>>>(pooled, pooled + G_*256, fc1w, fc1b, z1);
  k_fc2<<<G_, 128, 0, stream>>>(z1, fc2w, fc2b, z2);
  k_fc3<<<1, 64, 0, stream>>>(z2, fc3w, fc3b, out);
}